// Round 11
// baseline (122.789 us; speedup 1.0000x reference)
//
#include <hip/hip_runtime.h>
#include <hip/hip_fp16.h>
#include <math.h>

constexpr int E_EDGES = 4194304;
constexpr int N_PATCH = 524288;
constexpr int N_POSES = 2048;
constexpr float EPS_W = 1e-8f;

typedef int   iv4 __attribute__((ext_vector_type(4)));
typedef float fv4 __attribute__((ext_vector_type(4)));
typedef float fv2 __attribute__((ext_vector_type(2)));
typedef unsigned int uv2 __attribute__((ext_vector_type(2)));

// fast atan2: v_rcp + deg-7 odd minimax; max err ~1.5e-4 rad. Branch-cut sign
// from oy's actual sign; dangerous near-cut lanes are recomputed exactly (below).
__device__ __forceinline__ float fast_atan2f(float y, float x) {
    const float ax = __builtin_fabsf(x);
    const float ay = __builtin_fabsf(y);
    const float mx = fmaxf(ax, ay);
    const float mn = fminf(ax, ay);
    const float z  = mn * __builtin_amdgcn_rcpf(mx);
    const float z2 = z * z;
    float p = fmaf(z2, -0.0851330f, 0.1801410f);
    p = fmaf(z2, p, -0.3302995f);
    p = fmaf(z2, p, 0.9998660f);
    p = p * z;
    p = (ay > ax) ? (1.57079632679f - p) : p;
    p = (x < 0.0f) ? (3.14159265359f - p) : p;
    return __builtin_copysignf(p, y);
}

// quaternion double-rotate: o = conj(qT) * ((qS*l + sp) - tp) * ... shared helper
__device__ __forceinline__ void edge_transform(
    float lx, float ly, float lz,
    fv4 S0, fv4 S1, fv4 T0, fv4 T1,
    float& ox, float& oy, float& oz)
{
    const float qx = S0.w, qy = S1.x, qz = S1.y, qw = S1.z;
    const float t0 = 2.0f * (qy * lz - qz * ly);
    const float t1 = 2.0f * (qz * lx - qx * lz);
    const float t2 = 2.0f * (qx * ly - qy * lx);
    const float gx = lx + qw * t0 + (qy * t2 - qz * t1) + S0.x;
    const float gy = ly + qw * t1 + (qz * t0 - qx * t2) + S0.y;
    const float gz = lz + qw * t2 + (qx * t1 - qy * t0) + S0.z;

    const float dx = gx - T0.x;
    const float dy = gy - T0.y;
    const float dz = gz - T0.z;
    const float uqx = -T0.w, uqy = -T1.x, uqz = -T1.y, uqw = T1.z;

    const float u0 = 2.0f * (uqy * dz - uqz * dy);
    const float u1 = 2.0f * (uqz * dx - uqx * dz);
    const float u2 = 2.0f * (uqx * dy - uqy * dx);
    ox = dx + uqw * u0 + (uqy * u2 - uqz * u1);
    oy = dy + uqw * u1 + (uqz * u0 - uqx * u2);
    oz = dz + uqw * u2 + (uqx * u1 - uqy * u0);
}

// ---- fused prep: f16x4 patch table (8B/patch, 4MB: fits per-XCD L2) + padded poses ----
__global__ __launch_bounds__(256) void prep_all(
    const fv2*  __restrict__ pc_rt,
    const float* __restrict__ elev,
    const float* __restrict__ poses,
    uv2*        __restrict__ table_h,  // N_PATCH x packed f16 (lx,ly,lz,0)
    fv4*        __restrict__ poses8)
{
    const int j = blockIdx.x * blockDim.x + threadIdx.x;
    if (j < N_POSES) {
        const float* p = poses + (size_t)j * 7;
        fv4 a, b;
        a.x = p[0]; a.y = p[1]; a.z = p[2]; a.w = p[3];   // px py pz qx
        b.x = p[4]; b.y = p[5]; b.z = p[6]; b.w = 0.0f;   // qy qz qw -
        poses8[2 * j]     = a;
        poses8[2 * j + 1] = b;
    }
    if (j >= N_PATCH) return;
    const fv2 pc = pc_rt[j];
    const float phi = elev[j];
    float sphi, cphi, sth, cth;
    __sincosf(phi,  &sphi, &cphi);
    __sincosf(pc.y, &sth,  &cth);
    const float rcp = pc.x * cphi;
    __half2 a = __floats2half2_rn(rcp * cth, rcp * sth);
    __half2 b = __floats2half2_rn(pc.x * sphi, 0.0f);
    uv2 v;
    v.x = *reinterpret_cast<unsigned int*>(&a);
    v.y = *reinterpret_cast<unsigned int*>(&b);
    table_h[j] = v;
}

// ---- main: f16 table gather (1 line/edge, 4MB working set) + exact fixup for
//      flagged lanes. Flag bounds: |delta_o| <= 4.9e-4 * r_max(25.03) = 0.0123.
//      flag A: o_xy^2 < 1.5^2  -> unflagged angle err <= 0.0123/1.487*sy ~= 2.0
//      flag B: ox<0 && |oy|<0.03 -> unflagged |oy|>0.0177>delta: no 2pi flip ----
__global__ __launch_bounds__(1024, 8) void ba_main(
    const fv4*  __restrict__ poses8,
    const uv2*  __restrict__ table_h,
    const fv2*  __restrict__ pc2,      // exact planes for fixup lanes only
    const float* __restrict__ elevp,
    const float* __restrict__ scale,
    const fv4*  __restrict__ baseline4,
    const fv4*  __restrict__ weights4,
    const iv4*  __restrict__ patch_idx4,
    const iv4*  __restrict__ src_idx4,
    const iv4*  __restrict__ tgt_idx4,
    fv4*        __restrict__ out4)
{
    __shared__ fv4 sposes[N_POSES * 2];   // 64 KB
#pragma unroll
    for (int k = 0; k < (N_POSES * 2) / 1024; ++k)
        sposes[k * 1024 + threadIdx.x] = poses8[k * 1024 + threadIdx.x];
    __syncthreads();

    const int t = blockIdx.x * blockDim.x + threadIdx.x;  // one thread = 4 edges

    const iv4 pi = __builtin_nontemporal_load(patch_idx4 + t);
    const iv4 si = __builtin_nontemporal_load(src_idx4 + t);
    const iv4 ti = __builtin_nontemporal_load(tgt_idx4 + t);

    const fv4 bl01 = __builtin_nontemporal_load(baseline4 + 2 * t);
    const fv4 bl23 = __builtin_nontemporal_load(baseline4 + 2 * t + 1);
    const fv4 w01  = __builtin_nontemporal_load(weights4 + 2 * t);
    const fv4 w23  = __builtin_nontemporal_load(weights4 + 2 * t + 1);

    int pia[4], sia[4], gia[4];
#pragma unroll
    for (int i = 0; i < 4; ++i) {
        pia[i] = ((const int*)&pi)[i];
        sia[i] = ((const int*)&si)[i];
        gia[i] = ((const int*)&ti)[i];
    }

    // issue all 4 table gathers up front (1 random line per edge)
    uv2 L[4];
#pragma unroll
    for (int i = 0; i < 4; ++i) L[i] = table_h[pia[i]];
    __builtin_amdgcn_sched_barrier(0);

    const float sx = scale[0];
    const float sy = scale[1];

    float rx[4], ry[4];
#pragma unroll
    for (int i = 0; i < 4; ++i) {
        const __half2* hp = reinterpret_cast<const __half2*>(&L[i]);
        const float2 xy = __half22float2(hp[0]);
        const float2 zw = __half22float2(hp[1]);

        const fv4 S0 = sposes[2 * sia[i]];
        const fv4 S1 = sposes[2 * sia[i] + 1];
        const fv4 T0 = sposes[2 * gia[i]];
        const fv4 T1 = sposes[2 * gia[i] + 1];

        float ox, oy, oz;
        edge_transform(xy.x, xy.y, zw.x, S0, S1, T0, T1, ox, oy, oz);

        const float oxy2 = ox * ox + oy * oy;
        const bool danger = (oxy2 < 2.25f) ||
                            ((ox < 0.0f) && (__builtin_fabsf(oy) < 0.03f));
        if (danger) {
            // exact path (rare, ~1-2% of lanes): re-gather original planes
            const fv2  pc  = pc2[pia[i]];
            const float phi = elevp[pia[i]];
            float sphi, cphi, sth, cth;
            __sincosf(phi,  &sphi, &cphi);
            __sincosf(pc.y, &sth,  &cth);
            const float rcp = pc.x * cphi;
            edge_transform(rcp * cth, rcp * sth, pc.x * sphi,
                           S0, S1, T0, T1, ox, oy, oz);
        }

        rx[i] = __builtin_amdgcn_sqrtf(ox * ox + oy * oy + oz * oz) * sx;
        ry[i] = fast_atan2f(oy, ox) * sy;
    }

    fv4 o01, o23;
    o01.x = (rx[0] - bl01.x) * __builtin_amdgcn_sqrtf(w01.x + EPS_W);
    o01.y = (ry[0] - bl01.y) * __builtin_amdgcn_sqrtf(w01.y + EPS_W);
    o01.z = (rx[1] - bl01.z) * __builtin_amdgcn_sqrtf(w01.z + EPS_W);
    o01.w = (ry[1] - bl01.w) * __builtin_amdgcn_sqrtf(w01.w + EPS_W);
    o23.x = (rx[2] - bl23.x) * __builtin_amdgcn_sqrtf(w23.x + EPS_W);
    o23.y = (ry[2] - bl23.y) * __builtin_amdgcn_sqrtf(w23.y + EPS_W);
    o23.z = (rx[3] - bl23.z) * __builtin_amdgcn_sqrtf(w23.z + EPS_W);
    o23.w = (ry[3] - bl23.w) * __builtin_amdgcn_sqrtf(w23.w + EPS_W);
    out4[2 * t]     = o01;
    out4[2 * t + 1] = o23;
}

// ---- fallback A (R10 path, ws >= 64KB): two-plane f32 gathers, proven correct ----
__global__ __launch_bounds__(1024, 8) void ba_planes(
    const fv4*  __restrict__ poses8,
    const fv2*  __restrict__ pc2,
    const float* __restrict__ elevp,
    const float* __restrict__ scale,
    const fv4*  __restrict__ baseline4,
    const fv4*  __restrict__ weights4,
    const iv4*  __restrict__ patch_idx4,
    const iv4*  __restrict__ src_idx4,
    const iv4*  __restrict__ tgt_idx4,
    fv4*        __restrict__ out4)
{
    __shared__ fv4 sposes[N_POSES * 2];
#pragma unroll
    for (int k = 0; k < (N_POSES * 2) / 1024; ++k)
        sposes[k * 1024 + threadIdx.x] = poses8[k * 1024 + threadIdx.x];
    __syncthreads();

    const int t = blockIdx.x * blockDim.x + threadIdx.x;

    const iv4 pi = __builtin_nontemporal_load(patch_idx4 + t);
    const iv4 si = __builtin_nontemporal_load(src_idx4 + t);
    const iv4 ti = __builtin_nontemporal_load(tgt_idx4 + t);
    const fv4 bl01 = __builtin_nontemporal_load(baseline4 + 2 * t);
    const fv4 bl23 = __builtin_nontemporal_load(baseline4 + 2 * t + 1);
    const fv4 w01  = __builtin_nontemporal_load(weights4 + 2 * t);
    const fv4 w23  = __builtin_nontemporal_load(weights4 + 2 * t + 1);

    int pia[4], sia[4], gia[4];
#pragma unroll
    for (int i = 0; i < 4; ++i) {
        pia[i] = ((const int*)&pi)[i];
        sia[i] = ((const int*)&si)[i];
        gia[i] = ((const int*)&ti)[i];
    }

    fv2 pcv[4]; float ph[4];
#pragma unroll
    for (int i = 0; i < 4; ++i) {
        pcv[i] = pc2[pia[i]];
        ph[i]  = elevp[pia[i]];
    }
    __builtin_amdgcn_sched_barrier(0);

    const float sx = scale[0];
    const float sy = scale[1];

    float rx[4], ry[4];
#pragma unroll
    for (int i = 0; i < 4; ++i) {
        float sphi, cphi, sth, cth;
        __sincosf(ph[i],    &sphi, &cphi);
        __sincosf(pcv[i].y, &sth,  &cth);
        const float rcp = pcv[i].x * cphi;

        const fv4 S0 = sposes[2 * sia[i]];
        const fv4 S1 = sposes[2 * sia[i] + 1];
        const fv4 T0 = sposes[2 * gia[i]];
        const fv4 T1 = sposes[2 * gia[i] + 1];

        float ox, oy, oz;
        edge_transform(rcp * cth, rcp * sth, pcv[i].x * sphi,
                       S0, S1, T0, T1, ox, oy, oz);
        rx[i] = __builtin_amdgcn_sqrtf(ox * ox + oy * oy + oz * oz) * sx;
        ry[i] = fast_atan2f(oy, ox) * sy;
    }

    fv4 o01, o23;
    o01.x = (rx[0] - bl01.x) * __builtin_amdgcn_sqrtf(w01.x + EPS_W);
    o01.y = (ry[0] - bl01.y) * __builtin_amdgcn_sqrtf(w01.y + EPS_W);
    o01.z = (rx[1] - bl01.z) * __builtin_amdgcn_sqrtf(w01.z + EPS_W);
    o01.w = (ry[1] - bl01.w) * __builtin_amdgcn_sqrtf(w01.w + EPS_W);
    o23.x = (rx[2] - bl23.x) * __builtin_amdgcn_sqrtf(w23.x + EPS_W);
    o23.y = (ry[2] - bl23.y) * __builtin_amdgcn_sqrtf(w23.y + EPS_W);
    o23.z = (rx[3] - bl23.z) * __builtin_amdgcn_sqrtf(w23.z + EPS_W);
    o23.w = (ry[3] - bl23.w) * __builtin_amdgcn_sqrtf(w23.w + EPS_W);
    out4[2 * t]     = o01;
    out4[2 * t + 1] = o23;
}

__global__ __launch_bounds__(256) void prep_poses_only(
    const float* __restrict__ poses, fv4* __restrict__ poses8)
{
    const int j = blockIdx.x * blockDim.x + threadIdx.x;
    if (j >= N_POSES) return;
    const float* p = poses + (size_t)j * 7;
    fv4 a, b;
    a.x = p[0]; a.y = p[1]; a.z = p[2]; a.w = p[3];
    b.x = p[4]; b.y = p[5]; b.z = p[6]; b.w = 0.0f;
    poses8[2 * j]     = a;
    poses8[2 * j + 1] = b;
}

extern "C" void kernel_launch(void* const* d_in, const int* in_sizes, int n_in,
                              void* d_out, int out_size, void* d_ws, size_t ws_size,
                              hipStream_t stream) {
    const float* poses    = (const float*)d_in[0];
    const float* pc_rt    = (const float*)d_in[1];
    const float* elev     = (const float*)d_in[2];
    const float* scale    = (const float*)d_in[3];
    const fv4*   baseline = (const fv4*)d_in[4];
    const fv4*   weights4 = (const fv4*)d_in[5];
    const iv4*   patch_i  = (const iv4*)d_in[6];
    const iv4*   src_i    = (const iv4*)d_in[7];  // note: inv_idx at [7] unused (== patch_idx)
    const iv4*   src_idx  = (const iv4*)d_in[8];
    const iv4*   tgt_idx  = (const iv4*)d_in[9];
    fv4*         out      = (fv4*)d_out;
    (void)src_i;

    const size_t table_bytes  = (size_t)N_PATCH * 8;    // 4 MB f16 table
    const size_t poses8_bytes = (size_t)N_POSES * 32;   // 64 KB
    const int threads = E_EDGES / 4;                    // 1,048,576

    if (ws_size >= table_bytes + poses8_bytes) {
        uv2* table_h = (uv2*)d_ws;
        fv4* poses8  = (fv4*)((char*)d_ws + table_bytes);
        hipLaunchKernelGGL(prep_all, dim3(N_PATCH / 256), dim3(256), 0, stream,
                           (const fv2*)pc_rt, elev, poses, table_h, poses8);
        hipLaunchKernelGGL(ba_main, dim3(threads / 1024), dim3(1024), 0, stream,
                           (const fv4*)poses8, (const uv2*)table_h,
                           (const fv2*)pc_rt, elev, scale,
                           baseline, weights4, patch_i, src_idx, tgt_idx, out);
    } else if (ws_size >= poses8_bytes) {
        fv4* poses8 = (fv4*)d_ws;
        hipLaunchKernelGGL(prep_poses_only, dim3(N_POSES / 256), dim3(256), 0, stream,
                           poses, poses8);
        hipLaunchKernelGGL(ba_planes, dim3(threads / 1024), dim3(1024), 0, stream,
                           (const fv4*)poses8, (const fv2*)pc_rt, elev, scale,
                           baseline, weights4, patch_i, src_idx, tgt_idx, out);
    }
}

// Round 12
// 67.844 us; speedup vs baseline: 1.8099x; 1.8099x over previous
//
#include <hip/hip_runtime.h>
#include <hip/hip_fp16.h>
#include <math.h>

constexpr int E_EDGES = 4194304;
constexpr int N_PATCH = 524288;
constexpr int N_POSES = 2048;
constexpr float EPS_W = 1e-8f;

typedef int   iv2 __attribute__((ext_vector_type(2)));
typedef int   iv4 __attribute__((ext_vector_type(4)));
typedef float fv4 __attribute__((ext_vector_type(4)));
typedef float fv2 __attribute__((ext_vector_type(2)));
typedef unsigned int uv2 __attribute__((ext_vector_type(2)));

// fast atan2: v_rcp + deg-7 odd minimax; max err ~1.5e-4 rad (validated R9-R11).
__device__ __forceinline__ float fast_atan2f(float y, float x) {
    const float ax = __builtin_fabsf(x);
    const float ay = __builtin_fabsf(y);
    const float mx = fmaxf(ax, ay);
    const float mn = fminf(ax, ay);
    const float z  = mn * __builtin_amdgcn_rcpf(mx);
    const float z2 = z * z;
    float p = fmaf(z2, -0.0851330f, 0.1801410f);
    p = fmaf(z2, p, -0.3302995f);
    p = fmaf(z2, p, 0.9998660f);
    p = p * z;
    p = (ay > ax) ? (1.57079632679f - p) : p;
    p = (x < 0.0f) ? (3.14159265359f - p) : p;
    return __builtin_copysignf(p, y);
}

__device__ __forceinline__ void edge_transform(
    float lx, float ly, float lz,
    fv4 S0, fv4 S1, fv4 T0, fv4 T1,
    float& ox, float& oy, float& oz)
{
    const float qx = S0.w, qy = S1.x, qz = S1.y, qw = S1.z;
    const float t0 = 2.0f * (qy * lz - qz * ly);
    const float t1 = 2.0f * (qz * lx - qx * lz);
    const float t2 = 2.0f * (qx * ly - qy * lx);
    const float gx = lx + qw * t0 + (qy * t2 - qz * t1) + S0.x;
    const float gy = ly + qw * t1 + (qz * t0 - qx * t2) + S0.y;
    const float gz = lz + qw * t2 + (qx * t1 - qy * t0) + S0.z;

    const float dx = gx - T0.x;
    const float dy = gy - T0.y;
    const float dz = gz - T0.z;
    const float uqx = -T0.w, uqy = -T1.x, uqz = -T1.y, uqw = T1.z;

    const float u0 = 2.0f * (uqy * dz - uqz * dy);
    const float u1 = 2.0f * (uqz * dx - uqx * dz);
    const float u2 = 2.0f * (uqx * dy - uqy * dx);
    ox = dx + uqw * u0 + (uqy * u2 - uqz * u1);
    oy = dy + uqw * u1 + (uqz * u0 - uqx * u2);
    oz = dz + uqw * u2 + (uqx * u1 - uqy * u0);
}

// ---- fused prep: f16x4 patch table (8B/patch, 4MB = per-XCD L2 size) + padded poses ----
__global__ __launch_bounds__(256) void prep_all(
    const fv2*  __restrict__ pc_rt,
    const float* __restrict__ elev,
    const float* __restrict__ poses,
    uv2*        __restrict__ table_h,
    fv4*        __restrict__ poses8)
{
    const int j = blockIdx.x * blockDim.x + threadIdx.x;
    if (j < N_POSES) {
        const float* p = poses + (size_t)j * 7;
        fv4 a, b;
        a.x = p[0]; a.y = p[1]; a.z = p[2]; a.w = p[3];   // px py pz qx
        b.x = p[4]; b.y = p[5]; b.z = p[6]; b.w = 0.0f;   // qy qz qw -
        poses8[2 * j]     = a;
        poses8[2 * j + 1] = b;
    }
    if (j >= N_PATCH) return;
    const fv2 pc = pc_rt[j];
    const float phi = elev[j];
    float sphi, cphi, sth, cth;
    __sincosf(phi,  &sphi, &cphi);
    __sincosf(pc.y, &sth,  &cth);
    const float rcp = pc.x * cphi;
    __half2 a = __floats2half2_rn(rcp * cth, rcp * sth);
    __half2 b = __floats2half2_rn(pc.x * sphi, 0.0f);
    uv2 v;
    v.x = *reinterpret_cast<unsigned int*>(&a);
    v.y = *reinterpret_cast<unsigned int*>(&b);
    table_h[j] = v;
}

// ---- main: 2 edges/thread (low VGPR: R11's 4-edge fixup spilled to scratch ->
//      occupancy 3.7%, WRITE 168MB). f16 table gather (1 line/edge, 4MB) +
//      exact fixup for flagged lanes (~2%). bl/w loaded AFTER compute loop
//      to free 16 regs across the fixup region. ----
__global__ __launch_bounds__(1024, 8) void ba_main(
    const fv4*  __restrict__ poses8,
    const uv2*  __restrict__ table_h,
    const fv2*  __restrict__ pc2,
    const float* __restrict__ elevp,
    const float* __restrict__ scale,
    const fv4*  __restrict__ baseline4,  // index t = edges 2t,2t+1
    const fv4*  __restrict__ weights4,
    const iv2*  __restrict__ patch_idx2,
    const iv2*  __restrict__ src_idx2,
    const iv2*  __restrict__ tgt_idx2,
    fv4*        __restrict__ out4)       // index t
{
    __shared__ fv4 sposes[N_POSES * 2];   // 64 KB
#pragma unroll
    for (int k = 0; k < (N_POSES * 2) / 1024; ++k)
        sposes[k * 1024 + threadIdx.x] = poses8[k * 1024 + threadIdx.x];
    __syncthreads();

    const int t = blockIdx.x * blockDim.x + threadIdx.x;  // one thread = 2 edges

    const iv2 pi = __builtin_nontemporal_load(patch_idx2 + t);
    const iv2 si = __builtin_nontemporal_load(src_idx2 + t);
    const iv2 ti = __builtin_nontemporal_load(tgt_idx2 + t);

    int pia[2] = { pi.x, pi.y };
    int sia[2] = { si.x, si.y };
    int gia[2] = { ti.x, ti.y };

    // both table gathers up front (1 random line per edge)
    uv2 L[2];
    L[0] = table_h[pia[0]];
    L[1] = table_h[pia[1]];
    __builtin_amdgcn_sched_barrier(0);

    const float sx = scale[0];
    const float sy = scale[1];

    float rx[2], ry[2];
#pragma unroll
    for (int i = 0; i < 2; ++i) {
        const __half2* hp = reinterpret_cast<const __half2*>(&L[i]);
        const float2 xy = __half22float2(hp[0]);
        const float2 zw = __half22float2(hp[1]);

        const fv4 S0 = sposes[2 * sia[i]];
        const fv4 S1 = sposes[2 * sia[i] + 1];
        const fv4 T0 = sposes[2 * gia[i]];
        const fv4 T1 = sposes[2 * gia[i] + 1];

        float ox, oy, oz;
        edge_transform(xy.x, xy.y, zw.x, S0, S1, T0, T1, ox, oy, oz);

        // |delta_o| <= 4.9e-4 * r_max(25.03) = 0.0123.
        // flag A: o_xy^2 < 1.0 -> unflagged angle err <= 0.0123*sy ~= 3.0 (budget ok)
        // flag B: ox<0 && |oy|<0.025 -> unflagged |oy|>0.0127>delta: no 2pi flip
        const float oxy2 = ox * ox + oy * oy;
        const bool danger = (oxy2 < 1.0f) ||
                            ((ox < 0.0f) && (__builtin_fabsf(oy) < 0.025f));
        if (danger) {
            // exact path (rare ~2%): re-gather original planes, R9-proven math
            const fv2  pc  = pc2[pia[i]];
            const float phi = elevp[pia[i]];
            float sphi, cphi, sth, cth;
            __sincosf(phi,  &sphi, &cphi);
            __sincosf(pc.y, &sth,  &cth);
            const float rcp = pc.x * cphi;
            edge_transform(rcp * cth, rcp * sth, pc.x * sphi,
                           sposes[2 * sia[i]], sposes[2 * sia[i] + 1],
                           sposes[2 * gia[i]], sposes[2 * gia[i] + 1],
                           ox, oy, oz);
        }

        rx[i] = __builtin_amdgcn_sqrtf(ox * ox + oy * oy + oz * oz) * sx;
        ry[i] = fast_atan2f(oy, ox) * sy;
    }

    // streams loaded LATE (frees 16 VGPR during compute/fixup region)
    const fv4 bl = __builtin_nontemporal_load(baseline4 + t);
    const fv4 w  = __builtin_nontemporal_load(weights4 + t);

    fv4 o;
    o.x = (rx[0] - bl.x) * __builtin_amdgcn_sqrtf(w.x + EPS_W);
    o.y = (ry[0] - bl.y) * __builtin_amdgcn_sqrtf(w.y + EPS_W);
    o.z = (rx[1] - bl.z) * __builtin_amdgcn_sqrtf(w.z + EPS_W);
    o.w = (ry[1] - bl.w) * __builtin_amdgcn_sqrtf(w.w + EPS_W);
    out4[t] = o;   // 16 B/thread, fully coalesced
}

// ---- fallback (R10 path, proven): two-plane f32 gathers ----
__global__ __launch_bounds__(1024, 8) void ba_planes(
    const fv4*  __restrict__ poses8,
    const fv2*  __restrict__ pc2,
    const float* __restrict__ elevp,
    const float* __restrict__ scale,
    const fv4*  __restrict__ baseline4,
    const fv4*  __restrict__ weights4,
    const iv4*  __restrict__ patch_idx4,
    const iv4*  __restrict__ src_idx4,
    const iv4*  __restrict__ tgt_idx4,
    fv4*        __restrict__ out4)
{
    __shared__ fv4 sposes[N_POSES * 2];
#pragma unroll
    for (int k = 0; k < (N_POSES * 2) / 1024; ++k)
        sposes[k * 1024 + threadIdx.x] = poses8[k * 1024 + threadIdx.x];
    __syncthreads();

    const int t = blockIdx.x * blockDim.x + threadIdx.x;

    const iv4 pi = __builtin_nontemporal_load(patch_idx4 + t);
    const iv4 si = __builtin_nontemporal_load(src_idx4 + t);
    const iv4 ti = __builtin_nontemporal_load(tgt_idx4 + t);
    const fv4 bl01 = __builtin_nontemporal_load(baseline4 + 2 * t);
    const fv4 bl23 = __builtin_nontemporal_load(baseline4 + 2 * t + 1);
    const fv4 w01  = __builtin_nontemporal_load(weights4 + 2 * t);
    const fv4 w23  = __builtin_nontemporal_load(weights4 + 2 * t + 1);

    int pia[4], sia[4], gia[4];
#pragma unroll
    for (int i = 0; i < 4; ++i) {
        pia[i] = ((const int*)&pi)[i];
        sia[i] = ((const int*)&si)[i];
        gia[i] = ((const int*)&ti)[i];
    }

    fv2 pcv[4]; float ph[4];
#pragma unroll
    for (int i = 0; i < 4; ++i) {
        pcv[i] = pc2[pia[i]];
        ph[i]  = elevp[pia[i]];
    }
    __builtin_amdgcn_sched_barrier(0);

    const float sx = scale[0];
    const float sy = scale[1];

    float rx[4], ry[4];
#pragma unroll
    for (int i = 0; i < 4; ++i) {
        float sphi, cphi, sth, cth;
        __sincosf(ph[i],    &sphi, &cphi);
        __sincosf(pcv[i].y, &sth,  &cth);
        const float rcp = pcv[i].x * cphi;

        float ox, oy, oz;
        edge_transform(rcp * cth, rcp * sth, pcv[i].x * sphi,
                       sposes[2 * sia[i]], sposes[2 * sia[i] + 1],
                       sposes[2 * gia[i]], sposes[2 * gia[i] + 1],
                       ox, oy, oz);
        rx[i] = __builtin_amdgcn_sqrtf(ox * ox + oy * oy + oz * oz) * sx;
        ry[i] = fast_atan2f(oy, ox) * sy;
    }

    fv4 o01, o23;
    o01.x = (rx[0] - bl01.x) * __builtin_amdgcn_sqrtf(w01.x + EPS_W);
    o01.y = (ry[0] - bl01.y) * __builtin_amdgcn_sqrtf(w01.y + EPS_W);
    o01.z = (rx[1] - bl01.z) * __builtin_amdgcn_sqrtf(w01.z + EPS_W);
    o01.w = (ry[1] - bl01.w) * __builtin_amdgcn_sqrtf(w01.w + EPS_W);
    o23.x = (rx[2] - bl23.x) * __builtin_amdgcn_sqrtf(w23.x + EPS_W);
    o23.y = (ry[2] - bl23.y) * __builtin_amdgcn_sqrtf(w23.y + EPS_W);
    o23.z = (rx[3] - bl23.z) * __builtin_amdgcn_sqrtf(w23.z + EPS_W);
    o23.w = (ry[3] - bl23.w) * __builtin_amdgcn_sqrtf(w23.w + EPS_W);
    out4[2 * t]     = o01;
    out4[2 * t + 1] = o23;
}

__global__ __launch_bounds__(256) void prep_poses_only(
    const float* __restrict__ poses, fv4* __restrict__ poses8)
{
    const int j = blockIdx.x * blockDim.x + threadIdx.x;
    if (j >= N_POSES) return;
    const float* p = poses + (size_t)j * 7;
    fv4 a, b;
    a.x = p[0]; a.y = p[1]; a.z = p[2]; a.w = p[3];
    b.x = p[4]; b.y = p[5]; b.z = p[6]; b.w = 0.0f;
    poses8[2 * j]     = a;
    poses8[2 * j + 1] = b;
}

extern "C" void kernel_launch(void* const* d_in, const int* in_sizes, int n_in,
                              void* d_out, int out_size, void* d_ws, size_t ws_size,
                              hipStream_t stream) {
    const float* poses    = (const float*)d_in[0];
    const float* pc_rt    = (const float*)d_in[1];
    const float* elev     = (const float*)d_in[2];
    const float* scale    = (const float*)d_in[3];
    const fv4*   baseline = (const fv4*)d_in[4];
    const fv4*   weights4 = (const fv4*)d_in[5];
    void*        patch_i  = (void*)d_in[6];
    void*        src_idx  = (void*)d_in[8];
    void*        tgt_idx  = (void*)d_in[9];
    fv4*         out      = (fv4*)d_out;

    const size_t table_bytes  = (size_t)N_PATCH * 8;    // 4 MB f16 table
    const size_t poses8_bytes = (size_t)N_POSES * 32;   // 64 KB

    if (ws_size >= table_bytes + poses8_bytes) {
        uv2* table_h = (uv2*)d_ws;
        fv4* poses8  = (fv4*)((char*)d_ws + table_bytes);
        hipLaunchKernelGGL(prep_all, dim3(N_PATCH / 256), dim3(256), 0, stream,
                           (const fv2*)pc_rt, elev, poses, table_h, poses8);
        const int threads = E_EDGES / 2;  // 2,097,152
        hipLaunchKernelGGL(ba_main, dim3(threads / 1024), dim3(1024), 0, stream,
                           (const fv4*)poses8, (const uv2*)table_h,
                           (const fv2*)pc_rt, elev, scale,
                           baseline, weights4,
                           (const iv2*)patch_i, (const iv2*)src_idx,
                           (const iv2*)tgt_idx, out);
    } else if (ws_size >= poses8_bytes) {
        fv4* poses8 = (fv4*)d_ws;
        hipLaunchKernelGGL(prep_poses_only, dim3(N_POSES / 256), dim3(256), 0, stream,
                           poses, poses8);
        const int threads = E_EDGES / 4;
        hipLaunchKernelGGL(ba_planes, dim3(threads / 1024), dim3(1024), 0, stream,
                           (const fv4*)poses8, (const fv2*)pc_rt, elev, scale,
                           baseline, weights4,
                           (const iv4*)patch_i, (const iv4*)src_idx,
                           (const iv4*)tgt_idx, out);
    }
}